// Round 1
// baseline (8822.237 us; speedup 1.0000x reference)
//
#include <hip/hip_runtime.h>
#include <hip/hip_bf16.h>

#define DZ 128
#define DB 32
#define DSIN 32
#define DX 64
#define NB 64
#define TT 4096

typedef short v8s __attribute__((ext_vector_type(8)));
typedef float v4f __attribute__((ext_vector_type(4)));

// sum with xor-1 partner lane via DPP quad_perm [1,0,3,2] (VALU pipe, no LDS)
__device__ __forceinline__ float pair_sum(float x) {
  int xi = __builtin_bit_cast(int, x);
  int yi = __builtin_amdgcn_mov_dpp(xi, 0xB1, 0xF, 0xF, true);
  return x + __builtin_bit_cast(float, yi);
}

__device__ __forceinline__ short f2bf(float f) {
  __hip_bfloat16 h = __float2bfloat16(f);
  return *reinterpret_cast<short*>(&h);
}

// --- kernel 0: WCd[i] = sum_{j != i} AW[i][j] * (sum_k alphas[k]*clip[j][k]) ---
__global__ void k_prep(const float* __restrict__ AW, const float* __restrict__ alphas,
                       const float* __restrict__ clip, float* __restrict__ WCd) {
  __shared__ float cd[DZ];
  int j = threadIdx.x;
  float s = 0.f;
  for (int k = 0; k < DB; ++k) s = fmaf(alphas[k], clip[j * DB + k], s);
  cd[j] = s;
  __syncthreads();
  float acc = 0.f;
  for (int jj = 0; jj < DZ; ++jj)
    if (jj != j) acc = fmaf(AW[j * DZ + jj], cd[jj], acc);
  WCd[j] = acc;
}

// --- kernel 1: U[t][i] = h[i] - WCd[i] + sum_s C[i][s]*inp[t][s] ---
__global__ void k_u(const float* __restrict__ inp, const float* __restrict__ h,
                    const float* __restrict__ C, const float* __restrict__ WCd,
                    float* __restrict__ U) {
  int gid = blockIdx.x * blockDim.x + threadIdx.x;
  int t = gid >> 7, i = gid & 127;
  float u = h[i] - WCd[i];
  const float4* c4 = (const float4*)(C + i * DSIN);
  const float4* i4 = (const float4*)(inp + t * DSIN);
#pragma unroll
  for (int s = 0; s < 8; ++s) {
    float4 cv = c4[s], iv = i4[s];
    u = fmaf(cv.x, iv.x, u);
    u = fmaf(cv.y, iv.y, u);
    u = fmaf(cv.z, iv.z, u);
    u = fmaf(cv.w, iv.w, u);
  }
  U[gid] = u;
}

// --- kernel 2: the sequential scan. One block per batch, 256 threads = 2 lanes per z-dim. ---
__global__ __launch_bounds__(256, 1) void k_scan(
    const float* __restrict__ z0, const float* __restrict__ AW,
    const float* __restrict__ thetas, const float* __restrict__ alphas,
    const float* __restrict__ clip, const float* __restrict__ U,
    short* __restrict__ Z) {
  __shared__ __align__(16) float gbuf[2][DZ];
  const int b = blockIdx.x;
  const int tid = threadIdx.x;
  const int i = tid >> 1, hh = tid & 1;

  // W row half in registers (64 f32), diagonal zeroed
  float w[64];
  {
    const float4* wr = (const float4*)(AW + i * DZ + hh * 64);
#pragma unroll
    for (int r = 0; r < 16; ++r) {
      float4 v = wr[r];
      w[4 * r + 0] = v.x;
      w[4 * r + 1] = v.y;
      w[4 * r + 2] = v.z;
      w[4 * r + 3] = v.w;
    }
  }
  const float adiag = AW[i * DZ + i];
  {
    int dl = i - hh * 64;
    if (dl >= 0 && dl < 64) w[dl] = 0.f;
  }
  float th[16], nc[16], ak[16];
#pragma unroll
  for (int k = 0; k < 16; ++k) {
    th[k] = thetas[i * DB + hh * 16 + k];
    nc[k] = -clip[i * DB + hh * 16 + k];
    ak[k] = -0.82f * alphas[hh * 16 + k];
  }
  float z = z0[b * DZ + i];
  float u_cur = U[i];  // t = 0
  int buf = 0;
#pragma unroll 2
  for (int t = 0; t < TT; ++t) {
    int tn = (t + 1 < TT) ? t + 1 : t;
    float u_nxt = U[tn * DZ + i];  // prefetch; consumed next iteration

    // g partial over this lane's 16 k's:  g_i = sum_k (-0.82*alpha_k)*clamp(z-theta, -c, 0)
    float g0 = 0.f, g1 = 0.f;
#pragma unroll
    for (int k = 0; k < 16; k += 2) {
      g0 = fmaf(ak[k], __builtin_amdgcn_fmed3f(z - th[k], nc[k], 0.f), g0);
      g1 = fmaf(ak[k + 1], __builtin_amdgcn_fmed3f(z - th[k + 1], nc[k + 1], 0.f), g1);
    }
    float gi = pair_sum(g0 + g1);
    if (hh == 0) gbuf[buf][i] = gi;
    __syncthreads();

    // matvec half: m_i = sum_{j in half} W[i][j] * g[j]  (LDS broadcast reads)
    const float4* g4 = (const float4*)(&gbuf[buf][hh * 64]);
    float a0 = 0.f, a1 = 0.f, a2 = 0.f, a3 = 0.f;
#pragma unroll
    for (int r = 0; r < 16; ++r) {
      float4 gv = g4[r];
      a0 = fmaf(w[4 * r + 0], gv.x, a0);
      a1 = fmaf(w[4 * r + 1], gv.y, a1);
      a2 = fmaf(w[4 * r + 2], gv.z, a2);
      a3 = fmaf(w[4 * r + 3], gv.w, a3);
    }
    float m = pair_sum((a0 + a1) + (a2 + a3));
    z = fmaf(z, adiag, m + u_cur);
    u_cur = u_nxt;
    if (hh == 0) Z[(t * NB + b) * DZ + i] = f2bf(z);
    buf ^= 1;
  }
}

// --- kernel 3: out = Z(bf16, 262144x128) @ B_obs(128x64) via MFMA 16x16x32 bf16 ---
__global__ __launch_bounds__(256) void k_obs(const short* __restrict__ Z,
                                             const float* __restrict__ Bo,
                                             float* __restrict__ out) {
  const int lane = threadIdx.x & 63;
  const int wv = threadIdx.x >> 6;
  const int rl = lane & 15;   // A row / C col index
  const int g = lane >> 4;    // k-group

  // B fragments: bfr[n-tile][k-step], each lane holds B[k = ks*32+g*8+m][nt*16+rl]
  v8s bfr[4][4];
#pragma unroll
  for (int nt = 0; nt < 4; ++nt) {
#pragma unroll
    for (int ks = 0; ks < 4; ++ks) {
      v8s f;
#pragma unroll
      for (int m = 0; m < 8; ++m) {
        int k = ks * 32 + g * 8 + m;
        f[m] = f2bf(Bo[k * DX + nt * 16 + rl]);
      }
      bfr[nt][ks] = f;
    }
  }

#pragma unroll
  for (int it = 0; it < 4; ++it) {
    const int r0 = blockIdx.x * 256 + it * 64 + wv * 16;
    const short* zrow = Z + (r0 + rl) * DZ;
    v8s afr[4];
#pragma unroll
    for (int ks = 0; ks < 4; ++ks)
      afr[ks] = *(const v8s*)(zrow + ks * 32 + g * 8);
    v4f acc[4];
#pragma unroll
    for (int nt = 0; nt < 4; ++nt) acc[nt] = (v4f){0.f, 0.f, 0.f, 0.f};
#pragma unroll
    for (int nt = 0; nt < 4; ++nt) {
#pragma unroll
      for (int ks = 0; ks < 4; ++ks)
        acc[nt] = __builtin_amdgcn_mfma_f32_16x16x32_bf16(afr[ks], bfr[nt][ks], acc[nt], 0, 0, 0);
    }
#pragma unroll
    for (int nt = 0; nt < 4; ++nt) {
#pragma unroll
      for (int q = 0; q < 4; ++q)
        out[(r0 + g * 4 + q) * DX + nt * 16 + rl] = acc[nt][q];
    }
  }
}

extern "C" void kernel_launch(void* const* d_in, const int* in_sizes, int n_in,
                              void* d_out, int out_size, void* d_ws, size_t ws_size,
                              hipStream_t stream) {
  const float* z0 = (const float*)d_in[0];
  const float* inp = (const float*)d_in[1];
  const float* AW = (const float*)d_in[2];
  const float* h = (const float*)d_in[3];
  const float* thetas = (const float*)d_in[4];
  const float* alphas = (const float*)d_in[5];
  const float* clip = (const float*)d_in[6];
  const float* C = (const float*)d_in[7];
  const float* Bo = (const float*)d_in[8];
  float* out = (float*)d_out;

  char* ws = (char*)d_ws;
  float* WCd = (float*)ws;                                // 512 B
  float* U = (float*)(ws + 1024);                         // TT*128 f32 = 2 MiB
  short* Z = (short*)(ws + 1024 + (size_t)TT * DZ * 4);   // TT*64*128 bf16 = 64 MiB

  k_prep<<<1, 128, 0, stream>>>(AW, alphas, clip, WCd);
  k_u<<<(TT * DZ) / 256, 256, 0, stream>>>(inp, h, C, WCd, U);
  k_scan<<<NB, 256, 0, stream>>>(z0, AW, thetas, alphas, clip, U, Z);
  k_obs<<<(TT * NB) / 256, 256, 0, stream>>>(Z, Bo, out);
}

// Round 2
// 2078.958 us; speedup vs baseline: 4.2436x; 4.2436x over previous
//
#include <hip/hip_runtime.h>
#include <hip/hip_bf16.h>

#define DZ 128
#define DB 32
#define DSIN 32
#define DX 64
#define NB 64
#define TT 4096

typedef short v8s __attribute__((ext_vector_type(8)));
typedef float v4f __attribute__((ext_vector_type(4)));

// sum with xor-1 partner lane via DPP quad_perm [1,0,3,2] (VALU pipe, no LDS)
__device__ __forceinline__ float pair_sum(float x) {
  int xi = __builtin_bit_cast(int, x);
  int yi = __builtin_amdgcn_mov_dpp(xi, 0xB1, 0xF, 0xF, true);
  return x + __builtin_bit_cast(float, yi);
}

__device__ __forceinline__ short f2bf(float f) {
  __hip_bfloat16 h = __float2bfloat16(f);
  return *reinterpret_cast<short*>(&h);
}

// --- kernel 0: WCd[i] = sum_{j != i} AW[i][j] * (sum_k alphas[k]*clip[j][k]) ---
__global__ void k_prep(const float* __restrict__ AW, const float* __restrict__ alphas,
                       const float* __restrict__ clip, float* __restrict__ WCd) {
  __shared__ float cd[DZ];
  int j = threadIdx.x;
  float s = 0.f;
  for (int k = 0; k < DB; ++k) s = fmaf(alphas[k], clip[j * DB + k], s);
  cd[j] = s;
  __syncthreads();
  float acc = 0.f;
  for (int jj = 0; jj < DZ; ++jj)
    if (jj != j) acc = fmaf(AW[j * DZ + jj], cd[jj], acc);
  WCd[j] = acc;
}

// --- kernel 1: UT[i][t] = h[i] - WCd[i] + sum_s C[i][s]*inp[t][s]  (transposed) ---
__global__ void k_u(const float* __restrict__ inp, const float* __restrict__ h,
                    const float* __restrict__ C, const float* __restrict__ WCd,
                    float* __restrict__ UT) {
  int gid = blockIdx.x * blockDim.x + threadIdx.x;  // 128 * 1024 threads
  int i = gid >> 10;
  int t0 = (gid & 1023) * 4;
  float base = h[i] - WCd[i];
  const float4* c4 = (const float4*)(C + i * DSIN);
  float4 cv[8];
#pragma unroll
  for (int s = 0; s < 8; ++s) cv[s] = c4[s];
  float out[4];
#pragma unroll
  for (int tt = 0; tt < 4; ++tt) {
    const float4* i4 = (const float4*)(inp + (size_t)(t0 + tt) * DSIN);
    float u = base;
#pragma unroll
    for (int s = 0; s < 8; ++s) {
      float4 iv = i4[s];
      u = fmaf(cv[s].x, iv.x, u);
      u = fmaf(cv[s].y, iv.y, u);
      u = fmaf(cv[s].z, iv.z, u);
      u = fmaf(cv[s].w, iv.w, u);
    }
    out[tt] = u;
  }
  *(float4*)(UT + (size_t)i * TT + t0) = make_float4(out[0], out[1], out[2], out[3]);
}

// --- kernel 2: sequential scan. One block per batch, 256 threads = 2 lanes per z-dim. ---
__global__ __launch_bounds__(256, 1) void k_scan(
    const float* __restrict__ z0, const float* __restrict__ AW,
    const float* __restrict__ thetas, const float* __restrict__ alphas,
    const float* __restrict__ clip, const float* __restrict__ UT,
    short* __restrict__ Z) {
  // two halves of g live at +0 and +68 floats (bank-group disjoint for the
  // paired broadcast ds_read_b128: banks {4r..4r+3} vs {4r+4..4r+7})
  __shared__ __align__(16) float gbuf[2][136];
  const int b = blockIdx.x;
  const int tid = threadIdx.x;
  const int i = tid >> 1, hh = tid & 1;
  const int col0 = hh * 64;

  // W row half in registers, diagonal zeroed BRANCHLESSLY (no runtime array
  // index -> stays in VGPRs; round-0's w[dl]=0 pushed the array to scratch)
  float w[64];
  {
    const float4* wr = (const float4*)(AW + (size_t)i * DZ + col0);
#pragma unroll
    for (int r = 0; r < 16; ++r) {
      float4 v = wr[r];
      w[4 * r + 0] = (col0 + 4 * r + 0 == i) ? 0.f : v.x;
      w[4 * r + 1] = (col0 + 4 * r + 1 == i) ? 0.f : v.y;
      w[4 * r + 2] = (col0 + 4 * r + 2 == i) ? 0.f : v.z;
      w[4 * r + 3] = (col0 + 4 * r + 3 == i) ? 0.f : v.w;
    }
  }
  const float adiag = AW[(size_t)i * DZ + i];
  float th[16], nc[16], ak[16];
#pragma unroll
  for (int k = 0; k < 16; ++k) {
    th[k] = thetas[i * DB + hh * 16 + k];
    nc[k] = -clip[i * DB + hh * 16 + k];
    ak[k] = -0.82f * alphas[hh * 16 + k];
  }
  float z = z0[b * DZ + i];
  const int slot = i + (i >> 6) * 4;  // pad-aware slot for g[i]
  const float4* up = (const float4*)(UT + (size_t)i * TT);
  float4 ug = up[0];
  short* zp = Z + b * DZ + i;

#pragma unroll 1
  for (int tg = 0; tg < TT / 4; ++tg) {
    float4 ugn = up[(tg + 1 < TT / 4) ? tg + 1 : tg];  // prefetch next group
    float uarr[4] = {ug.x, ug.y, ug.z, ug.w};
#pragma unroll
    for (int q = 0; q < 4; ++q) {
      float* gq = gbuf[q & 1];
      // g_i = sum_k (-0.82*alpha_k)*clamp(z-theta, -c, 0)  (this lane's 16 k's)
      float g0 = 0.f, g1 = 0.f;
#pragma unroll
      for (int k = 0; k < 16; k += 2) {
        g0 = fmaf(ak[k], __builtin_amdgcn_fmed3f(z - th[k], nc[k], 0.f), g0);
        g1 = fmaf(ak[k + 1], __builtin_amdgcn_fmed3f(z - th[k + 1], nc[k + 1], 0.f), g1);
      }
      float gi = pair_sum(g0 + g1);
      if (hh == 0) gq[slot] = gi;
      // manual barrier: drain LDS only — no vmcnt(0), stores/loads keep flying
      asm volatile("s_waitcnt lgkmcnt(0)\n\ts_barrier" ::: "memory");

      // matvec half: m_i = sum_{j in half} W[i][j] * g[j]  (broadcast LDS reads)
      const float4* g4 = (const float4*)(gq + hh * 68);
      float a0 = 0.f, a1 = 0.f, a2 = 0.f, a3 = 0.f;
#pragma unroll
      for (int r = 0; r < 16; ++r) {
        float4 gv = g4[r];
        a0 = fmaf(w[4 * r + 0], gv.x, a0);
        a1 = fmaf(w[4 * r + 1], gv.y, a1);
        a2 = fmaf(w[4 * r + 2], gv.z, a2);
        a3 = fmaf(w[4 * r + 3], gv.w, a3);
      }
      float m = pair_sum((a0 + a1) + (a2 + a3));
      z = fmaf(z, adiag, m + uarr[q]);
      if (hh == 0) zp[(size_t)(tg * 4 + q) * (NB * DZ)] = f2bf(z);
    }
    ug = ugn;
  }
}

// --- kernel 3: out = Z(bf16, 262144x128) @ B_obs(128x64) via MFMA 16x16x32 bf16 ---
__global__ __launch_bounds__(256) void k_obs(const short* __restrict__ Z,
                                             const float* __restrict__ Bo,
                                             float* __restrict__ out) {
  const int lane = threadIdx.x & 63;
  const int wv = threadIdx.x >> 6;
  const int rl = lane & 15;  // A row / C col index
  const int g = lane >> 4;   // k-group

  v8s bfr[4][4];
#pragma unroll
  for (int nt = 0; nt < 4; ++nt) {
#pragma unroll
    for (int ks = 0; ks < 4; ++ks) {
      v8s f;
#pragma unroll
      for (int m = 0; m < 8; ++m) {
        int k = ks * 32 + g * 8 + m;
        f[m] = f2bf(Bo[k * DX + nt * 16 + rl]);
      }
      bfr[nt][ks] = f;
    }
  }

#pragma unroll
  for (int it = 0; it < 4; ++it) {
    const int r0 = blockIdx.x * 256 + it * 64 + wv * 16;
    const short* zrow = Z + (size_t)(r0 + rl) * DZ;
    v8s afr[4];
#pragma unroll
    for (int ks = 0; ks < 4; ++ks)
      afr[ks] = *(const v8s*)(zrow + ks * 32 + g * 8);
    v4f acc[4];
#pragma unroll
    for (int nt = 0; nt < 4; ++nt) acc[nt] = (v4f){0.f, 0.f, 0.f, 0.f};
#pragma unroll
    for (int nt = 0; nt < 4; ++nt) {
#pragma unroll
      for (int ks = 0; ks < 4; ++ks)
        acc[nt] = __builtin_amdgcn_mfma_f32_16x16x32_bf16(afr[ks], bfr[nt][ks], acc[nt], 0, 0, 0);
    }
#pragma unroll
    for (int nt = 0; nt < 4; ++nt) {
#pragma unroll
      for (int q = 0; q < 4; ++q)
        out[(size_t)(r0 + g * 4 + q) * DX + nt * 16 + rl] = acc[nt][q];
    }
  }
}

extern "C" void kernel_launch(void* const* d_in, const int* in_sizes, int n_in,
                              void* d_out, int out_size, void* d_ws, size_t ws_size,
                              hipStream_t stream) {
  const float* z0 = (const float*)d_in[0];
  const float* inp = (const float*)d_in[1];
  const float* AW = (const float*)d_in[2];
  const float* h = (const float*)d_in[3];
  const float* thetas = (const float*)d_in[4];
  const float* alphas = (const float*)d_in[5];
  const float* clip = (const float*)d_in[6];
  const float* C = (const float*)d_in[7];
  const float* Bo = (const float*)d_in[8];
  float* out = (float*)d_out;

  char* ws = (char*)d_ws;
  float* WCd = (float*)ws;                                 // 512 B
  float* UT = (float*)(ws + 1024);                         // 128*TT f32 = 2 MiB
  short* Z = (short*)(ws + 1024 + (size_t)TT * DZ * 4);    // TT*64*128 bf16 = 64 MiB

  k_prep<<<1, 128, 0, stream>>>(AW, alphas, clip, WCd);
  k_u<<<(DZ * TT / 4) / 256, 256, 0, stream>>>(inp, h, C, WCd, UT);
  k_scan<<<NB, 256, 0, stream>>>(z0, AW, thetas, alphas, clip, UT, Z);
  k_obs<<<(TT * NB) / 256, 256, 0, stream>>>(Z, Bo, out);
}